// Round 6
// baseline (34.352 us; speedup 1.0000x reference)
//
#include <hip/hip_runtime.h>
#include <math.h>

#define NDET 10647
#define NB 4
#define NCLS 80
#define CAP 160   // per-(image,class) bucket capacity; expected ~66±8, 160 ≈ 11 sigma

// numerically-stable sigmoid, mirrors jax.nn.sigmoid's f32 behavior
__device__ __forceinline__ float sigmoidf_ref(float x) {
    if (x >= 0.f) {
        return 1.f / (1.f + expf(-x));
    } else {
        float e = expf(x);
        return e / (1.f + e);
    }
}

// Thread-per-cell decode: for fixed channel j, consecutive (h*S+w) cells are
// contiguous in memory -> every load in the j-loop is a fully coalesced
// 256B/wave read. 85 independent loads per thread = deep MLP, no LDS, no
// syncthreads. Class argmax on RAW logits (sigmoid monotonic; first-max
// strict-> tie rule preserved by in-order 4-chain merge).
template <int S>
__device__ __forceinline__ void decode_cell(
    const float* __restrict__ feat, int b, int a, int cell, int off, float sx,
    float anchw, float anchh, float* __restrict__ det, float* __restrict__ keep,
    int* __restrict__ counts, float4* __restrict__ bbox,
    float* __restrict__ bconf, int* __restrict__ bidx)
{
    const int SS = S * S;
    const int h = cell / S;
    const int w = cell - h * S;
    const float* p = feat + ((size_t)(b * 255 + a * 85)) * SS + cell;

    float t0 = p[0 * SS];
    float t1 = p[1 * SS];
    float t2 = p[2 * SS];
    float t3 = p[3 * SS];
    float t4 = p[4 * SS];

    // load all 80 class logits into registers (compile-time indices only)
    float v[80];
#pragma unroll
    for (int j = 0; j < 80; ++j) v[j] = p[(size_t)(5 + j) * SS];

    // 4 independent chains over contiguous ranges, merged in index order
    float m0 = v[0], m1 = v[20], m2 = v[40], m3 = v[60];
    int i0 = 0, i1 = 20, i2 = 40, i3 = 60;
#pragma unroll
    for (int j = 1; j < 20; ++j) {
        if (v[j]      > m0) { m0 = v[j];      i0 = j; }
        if (v[20 + j] > m1) { m1 = v[20 + j]; i1 = 20 + j; }
        if (v[40 + j] > m2) { m2 = v[40 + j]; i2 = 40 + j; }
        if (v[60 + j] > m3) { m3 = v[60 + j]; i3 = 60 + j; }
    }
    float best = m0; int cls = i0;
    if (m1 > best) { best = m1; cls = i1; }
    if (m2 > best) { best = m2; cls = i2; }
    if (m3 > best) { best = m3; cls = i3; }

    float x  = (sigmoidf_ref(t0) + (float)w) * sx;
    float y  = (sigmoidf_ref(t1) + (float)h) * sx;
    float bw = expf(t2) * anchw * sx;
    float bh = expf(t3) * anchh * sx;
    float conf = sigmoidf_ref(t4);

    float b0 = x - bw * 0.5f;
    float b1 = x + bw * 0.5f;
    float b2 = y - bh * 0.5f;
    float b3 = y + bh * 0.5f;

    const int n = off + (w * S + h) * 3 + a;
    // det rows are 6 floats = 24B -> always 8B aligned: three float2 stores
    float2* o = reinterpret_cast<float2*>(det + ((size_t)b * NDET + n) * 6);
    o[0] = make_float2(b0, b1);
    o[1] = make_float2(b2, b3);
    o[2] = make_float2(conf, (float)cls);

    if (conf > 0.5f) {
        int bk = b * NCLS + cls;
        int pos = atomicAdd(&counts[bk], 1);
        if (pos < CAP) {
            int slot = bk * CAP + pos;
            bbox[slot]  = make_float4(b0, b1, b2, b3);
            bconf[slot] = conf;
            bidx[slot]  = n;
        }
    } else {
        keep[(size_t)b * NDET + n] = 0.f;
    }
}

// grid = (57, 3, 4): x = 64-cell chunk (0-42: S=52, 43-53: S=26, 54-56: S=13),
// y = anchor, z = image. 684 blocks x 1 wave -> all CUs pull HBM concurrently.
__global__ __launch_bounds__(64) void decode_kernel(
    const float* __restrict__ f0, const float* __restrict__ f1,
    const float* __restrict__ f2, float* __restrict__ det,
    float* __restrict__ keep, int* __restrict__ counts,
    float4* __restrict__ bbox, float* __restrict__ bconf, int* __restrict__ bidx)
{
    const int b = blockIdx.z;
    const int a = blockIdx.y;
    const int cx = blockIdx.x;
    const int tid = threadIdx.x;

    if (cx < 43) {
        int cell = cx * 64 + tid;
        if (cell < 52 * 52) {
            const float aw[3] = {10.f, 16.f, 33.f}, ah[3] = {13.f, 30.f, 23.f};
            decode_cell<52>(f0, b, a, cell, 0, 8.f, aw[a], ah[a],
                            det, keep, counts, bbox, bconf, bidx);
        }
    } else if (cx < 54) {
        int cell = (cx - 43) * 64 + tid;
        if (cell < 26 * 26) {
            const float aw[3] = {30.f, 62.f, 59.f}, ah[3] = {61.f, 45.f, 119.f};
            decode_cell<26>(f1, b, a, cell, 8112, 16.f, aw[a], ah[a],
                            det, keep, counts, bbox, bconf, bidx);
        }
    } else {
        int cell = (cx - 54) * 64 + tid;
        if (cell < 13 * 13) {
            const float aw[3] = {116.f, 156.f, 373.f}, ah[3] = {90.f, 198.f, 326.f};
            decode_cell<13>(f2, b, a, cell, 10140, 32.f, aw[a], ah[a],
                            det, keep, counts, bbox, bconf, bidx);
        }
    }
}

// One block per (image,class) bucket. Bucket staged in LDS; each thread owns
// one entry and does a branch-free scan over the whole bucket (order-invariant
// OR, so atomic fill order cannot change the output).
__global__ __launch_bounds__(192) void nms_kernel(
    const int* __restrict__ counts, const float4* __restrict__ bbox,
    const float* __restrict__ bconf, const int* __restrict__ bidx,
    float* __restrict__ keep)
{
    const int bk = blockIdx.x;          // b*NCLS + cls
    const int b = bk / NCLS;
    int cnt = counts[bk];
    if (cnt > CAP) cnt = CAP;

    __shared__ float4 sb[CAP];
    __shared__ float  sc[CAP];
    __shared__ int    si[CAP];
    const int t = threadIdx.x;
    if (t < cnt) {
        sb[t] = bbox[bk * CAP + t];
        sc[t] = bconf[bk * CAP + t];
        si[t] = bidx[bk * CAP + t];
    }
    __syncthreads();
    if (t >= cnt) return;

    float4 me = sb[t];
    float ci = sc[t];
    // replicate reference exactly: area uses (b2-b0) x (b3-b1)
    float ai = fmaxf(me.z - me.x + 1.f, 0.f) * fmaxf(me.w - me.y + 1.f, 0.f);
    float kv = 0.f;
    for (int j = 0; j < cnt; ++j) {
        float cj = sc[j];
        float4 c = sb[j];
        float xmin = fmaxf(me.x, c.x);
        float ymin = fmaxf(me.y, c.y);
        float xmax = fminf(me.z, c.z);
        float ymax = fminf(me.w, c.w);
        float inter = fmaxf(xmax - xmin + 1.f, 0.f) * fmaxf(ymax - ymin + 1.f, 0.f);
        float aj = fmaxf(c.z - c.x + 1.f, 0.f) * fmaxf(c.w - c.y + 1.f, 0.f);
        float iou = inter / (ai + aj - inter);
        // NaN (0/0) compares false, same as numpy
        if (cj > ci && iou > 0.4f) kv = 1.f;
    }
    keep[(size_t)b * NDET + si[t]] = kv;
}

extern "C" void kernel_launch(void* const* d_in, const int* in_sizes, int n_in,
                              void* d_out, int out_size, void* d_ws, size_t ws_size,
                              hipStream_t stream) {
    const float* f0 = (const float*)d_in[0];
    const float* f1 = (const float*)d_in[1];
    const float* f2 = (const float*)d_in[2];
    float* det  = (float*)d_out;                       // (B, 10647, 6)
    float* keep = det + (size_t)NB * NDET * 6;         // (B, 10647) as 0/1 floats

    // workspace layout
    char* ws = (char*)d_ws;
    int* counts = (int*)ws;                             ws += NB * NCLS * sizeof(int);
    ws = (char*)(((uintptr_t)ws + 15) & ~(uintptr_t)15);
    float4* bbox = (float4*)ws;                         ws += (size_t)NB * NCLS * CAP * sizeof(float4);
    float* bconf = (float*)ws;                          ws += (size_t)NB * NCLS * CAP * sizeof(float);
    int*   bidx  = (int*)ws;

    hipMemsetAsync(counts, 0, NB * NCLS * sizeof(int), stream);

    dim3 gdec(57, 3, NB);
    hipLaunchKernelGGL(decode_kernel, gdec, dim3(64), 0, stream,
                       f0, f1, f2, det, keep, counts, bbox, bconf, bidx);

    hipLaunchKernelGGL(nms_kernel, dim3(NB * NCLS), dim3(192), 0, stream,
                       counts, bbox, bconf, bidx, keep);
}